// Round 7
// baseline (442.760 us; speedup 1.0000x reference)
//
#include <hip/hip_runtime.h>
#include <math.h>

#define EMB 512
#define SEQL 1024
#define NBATCH 2
#define NHEAD 8
#define FFDIM 2048
#define NLAYER 4
#define NROWS (NBATCH*SEQL)
#define CHUNK 128
#define NCH (SEQL/CHUNK)
#define QSTR 1536
#define LN_EPS_F 1e-5f
#define ATT_EPS_F 1e-6f

typedef __bf16 bf16x8 __attribute__((ext_vector_type(8)));
typedef float f32x4 __attribute__((ext_vector_type(4)));

__device__ __forceinline__ unsigned short f2bf(float f) {
    unsigned int u = __float_as_uint(f);
    u += 0x7FFFu + ((u >> 16) & 1u);
    return (unsigned short)(u >> 16);
}
__device__ __forceinline__ float bf2f(unsigned short x) {
    return __uint_as_float(((unsigned int)x) << 16);
}
__device__ __forceinline__ void gl_lds16(const unsigned short* g, unsigned short* l) {
    __builtin_amdgcn_global_load_lds(
        (__attribute__((address_space(1))) void*)const_cast<unsigned short*>(g),
        (__attribute__((address_space(3))) void*)l, 16, 0, 0);
}

// ---------------- embedding + shift-right(SOS), writes fp32 X and bf16 Xb ----------------
__global__ void k_embed(const int* __restrict__ value, const int* __restrict__ depth,
                        const int* __restrict__ pos, const float* __restrict__ sos,
                        const float* __restrict__ tok, const float* __restrict__ dep,
                        const float* __restrict__ spa, float* __restrict__ X,
                        unsigned short* __restrict__ Xb) {
    int row = blockIdx.x;
    int n = row / SEQL, s = row % SEQL;
    int e = threadIdx.x * 4;
    float4 o;
    if (s == 0) {
        o = *(const float4*)(sos + e);
    } else {
        int sp = s - 1;
        int tv = value[n*SEQL + sp];
        int dv = depth[n*SEQL + sp];
        float4 a = *(const float4*)(tok + (size_t)tv*EMB + e);
        float4 b = *(const float4*)(dep + (size_t)dv*EMB + e);
        o.x = a.x+b.x; o.y = a.y+b.y; o.z = a.z+b.z; o.w = a.w+b.w;
#pragma unroll
        for (int ax = 0; ax < 3; ++ax) {
            int p = pos[((size_t)ax*NBATCH + n)*SEQL + sp];
            float4 c = *(const float4*)(spa + ((size_t)ax*257 + p)*EMB + e);
            o.x += c.x; o.y += c.y; o.z += c.z; o.w += c.w;
        }
    }
    *(float4*)(X + (size_t)row*EMB + e) = o;
    ushort4 ob; ob.x = f2bf(o.x); ob.y = f2bf(o.y); ob.z = f2bf(o.z); ob.w = f2bf(o.w);
    *(ushort4*)(Xb + (size_t)row*EMB + e) = ob;
}

// ---------------- weight convert, ALL layers + qkv bias pack, one launch ----------------
__global__ __launch_bounds__(256) void k_wconv(
        const float* __restrict__ Wq0, const float* __restrict__ Wk0, const float* __restrict__ Wv0,
        const float* __restrict__ Wo0, const float* __restrict__ W10, const float* __restrict__ W20,
        const float* __restrict__ bq0, const float* __restrict__ bk0, const float* __restrict__ bv0,
        unsigned short* __restrict__ wAll, float* __restrict__ bqkv) {
    int idx = blockIdx.x*256 + threadIdx.x;
    if (idx >= 1572864) {
        int t = idx - 1572864;
        if (t < 6144) {
            int L = t / 1536, c = t % 1536;
            float v = (c < 512) ? bq0[L*512 + c] : (c < 1024) ? bk0[L*512 + c - 512] : bv0[L*512 + c - 1024];
            bqkv[L*1536 + c] = v;
        }
        return;
    }
    int L = idx / 393216;
    int t0 = idx % 393216;
    const float* Wq = Wq0 + (size_t)L*EMB*EMB;
    const float* Wk = Wk0 + (size_t)L*EMB*EMB;
    const float* Wv = Wv0 + (size_t)L*EMB*EMB;
    const float* Wo = Wo0 + (size_t)L*EMB*EMB;
    const float* W1 = W10 + (size_t)L*EMB*FFDIM;
    const float* W2 = W20 + (size_t)L*FFDIM*EMB;
    unsigned short* lay = wAll + (size_t)L*3145728;
    unsigned short* qkvT = lay;
    unsigned short* woT  = lay + 786432;
    unsigned short* w1T  = lay + 1048576;
    unsigned short* w2T  = lay + 2097152;

    const float* src; unsigned short* dst; size_t soff; size_t doff;
    if (t0 < 131072) {
        int sub = t0 >> 15, t = t0 & 32767;
        int kb = t >> 9, n = t & 511;
        src = (sub == 0) ? Wq : (sub == 1) ? Wk : (sub == 2) ? Wv : Wo;
        soff = (size_t)kb*8*512 + n;
        if (sub < 3) { dst = qkvT; doff = ((size_t)kb*1536 + sub*512 + n)*8; }
        else         { dst = woT;  doff = ((size_t)kb*512 + n)*8; }
        unsigned int p[4];
#pragma unroll
        for (int t2 = 0; t2 < 4; ++t2) {
            unsigned int lo = f2bf(src[soff + (size_t)(2*t2)*512]);
            unsigned int hi = f2bf(src[soff + (size_t)(2*t2+1)*512]);
            p[t2] = lo | (hi << 16);
        }
        *(uint4*)(dst + doff) = make_uint4(p[0], p[1], p[2], p[3]);
    } else if (t0 < 262144) {
        int t = t0 - 131072;
        int kb = t >> 11, n = t & 2047;
        soff = (size_t)kb*8*2048 + n;
        doff = ((size_t)kb*2048 + n)*8;
        unsigned int p[4];
#pragma unroll
        for (int t2 = 0; t2 < 4; ++t2) {
            unsigned int lo = f2bf(W1[soff + (size_t)(2*t2)*2048]);
            unsigned int hi = f2bf(W1[soff + (size_t)(2*t2+1)*2048]);
            p[t2] = lo | (hi << 16);
        }
        *(uint4*)(w1T + doff) = make_uint4(p[0], p[1], p[2], p[3]);
    } else {
        int t = t0 - 262144;
        int kb = t >> 9, n = t & 511;
        soff = (size_t)kb*8*512 + n;
        doff = ((size_t)kb*512 + n)*8;
        unsigned int p[4];
#pragma unroll
        for (int t2 = 0; t2 < 4; ++t2) {
            unsigned int lo = f2bf(W2[soff + (size_t)(2*t2)*512]);
            unsigned int hi = f2bf(W2[soff + (size_t)(2*t2+1)*512]);
            p[t2] = lo | (hi << 16);
        }
        *(uint4*)(w2T + doff) = make_uint4(p[0], p[1], p[2], p[3]);
    }
}

// ---------------- bf16 MFMA GEMM, WR x WC waves, optional split-K ----------------
// ACT: 0 = none -> fp32 Cf (+ z*1048576 per k-slice, bias only on slice 0)
//      3 = gelu -> bf16 Cb ; 4 = fused QKV epilogue -> bf16 Cb
template<int BM, int BN, int WR, int WC, int ACT, int KS>
__global__ __launch_bounds__(WR*WC*64) void k_mgemm(
        const unsigned short* __restrict__ A, const unsigned short* __restrict__ Wt,
        const float* __restrict__ bias, const int* __restrict__ maskv,
        float* __restrict__ Cf, unsigned short* __restrict__ Cb,
        int N, int K, int lda, int ldc) {
    constexpr int THREADS = WR*WC*64;
    constexpr int WM = BM/WR, WN = BN/WC;
    constexpr int FM = WM/16, FN = WN/16;
    __shared__ __align__(16) unsigned short As[BM*32];
    __shared__ __align__(16) unsigned short Bs[BN*32];
    int tid = threadIdx.x;
    int lane = tid & 63;
    int l15 = lane & 15, lg = lane >> 4;
    int wid = tid >> 6;
    int wm = (wid / WC) * WM, wn = (wid % WC) * WN;
    int bm = blockIdx.y * BM, bn = blockIdx.x * BN;
    int kz = blockIdx.z;
    int ksl = K / KS;
    int kbeg = kz * ksl, kend = kbeg + ksl;

    f32x4 acc[FM][FN] = {};

    int a_off = (wm + l15)*32 + lg*8;
    int b_off = lg*BN*8 + (wn + l15)*8;

    for (int k0 = kbeg; k0 < kend; k0 += 32) {
#pragma unroll
        for (int i = 0; i < BM*4/THREADS; ++i) {
            int s = tid + i*THREADS;
            int m = s >> 2, kq = s & 3;
            gl_lds16(A + (size_t)(bm + m)*lda + k0 + kq*8, &As[s*8]);
        }
#pragma unroll
        for (int i = 0; i < BN*4/THREADS; ++i) {
            int s = tid + i*THREADS;
            int kb = s / BN, n = s - kb*BN;
            gl_lds16(Wt + ((size_t)(k0/8 + kb)*N + bn + n)*8, &Bs[s*8]);
        }
        __syncthreads();
        bf16x8 af[FM], bfr[FN];
#pragma unroll
        for (int mi = 0; mi < FM; ++mi) af[mi] = *(const bf16x8*)&As[a_off + mi*512];
#pragma unroll
        for (int ni = 0; ni < FN; ++ni) bfr[ni] = *(const bf16x8*)&Bs[b_off + ni*128];
#pragma unroll
        for (int mi = 0; mi < FM; ++mi)
#pragma unroll
            for (int ni = 0; ni < FN; ++ni)
                acc[mi][ni] = __builtin_amdgcn_mfma_f32_16x16x32_bf16(af[mi], bfr[ni], acc[mi][ni], 0, 0, 0);
        __syncthreads();
    }

    int r0 = bm + wm + lg*4;
    int c0 = bn + wn + l15;
    float* Cfz = Cf + (size_t)kz * 1048576;
#pragma unroll
    for (int mi = 0; mi < FM; ++mi) {
#pragma unroll
        for (int ni = 0; ni < FN; ++ni) {
            int col = c0 + ni*16;
#pragma unroll
            for (int j = 0; j < 4; ++j) {
                int row = r0 + mi*16 + j;
                float c = acc[mi][ni][j];
                if (KS == 1 || kz == 0) c += bias[col];
                if (ACT == 4) {
                    int reg = col >> 9;
                    if (reg == 0) { c = (c > 0.f) ? c + 1.f : expf(c); }
                    else if (reg == 1) { c = (c > 0.f) ? c + 1.f : expf(c); c *= (maskv[row] != 0) ? 1.f : 0.f; }
                    Cb[(size_t)row*ldc + col] = f2bf(c);
                } else if (ACT == 3) {
                    c = 0.5f * c * (1.f + erff(c * 0.70710678118654752f));
                    Cb[(size_t)row*ldc + col] = f2bf(c);
                } else {
                    Cfz[(size_t)row*ldc + col] = c;
                }
            }
        }
    }
}

// ---------------- per-chunk partial K^T V (64x64) and sum(k) (64), bf16 in ----------------
__global__ __launch_bounds__(256) void k_cpart(
        const unsigned short* __restrict__ QKVb, float* __restrict__ Mpart, float* __restrict__ Upart) {
    int b = blockIdx.x;
    int c = b % NCH, h = (b / NCH) % NHEAD, n = b / (NCH * NHEAD);
    const unsigned short* Kp = QKVb + (size_t)(n*SEQL + c*CHUNK)*QSTR + 512 + h*64;
    const unsigned short* Vp = Kp + 512;
    __shared__ float Ks[8][64], Vs[8][64];
    int tid = threadIdx.x;
    int dk = tid >> 2, dv0 = (tid & 3) * 16;
    int lr = tid >> 5, lc = (tid & 31) * 2;
    float acc[16] = {};
    float uacc = 0.f;
    for (int s0 = 0; s0 < CHUNK; s0 += 8) {
        ushort2 k2 = *(const ushort2*)(Kp + (size_t)(s0 + lr)*QSTR + lc);
        ushort2 v2 = *(const ushort2*)(Vp + (size_t)(s0 + lr)*QSTR + lc);
        Ks[lr][lc] = bf2f(k2.x); Ks[lr][lc+1] = bf2f(k2.y);
        Vs[lr][lc] = bf2f(v2.x); Vs[lr][lc+1] = bf2f(v2.y);
        __syncthreads();
#pragma unroll
        for (int ss = 0; ss < 8; ++ss) {
            float kk = Ks[ss][dk];
#pragma unroll
            for (int j = 0; j < 16; ++j) acc[j] += kk * Vs[ss][dv0 + j];
        }
        if (tid < 64) {
#pragma unroll
            for (int ss = 0; ss < 8; ++ss) uacc += Ks[ss][tid];
        }
        __syncthreads();
    }
    size_t base = ((size_t)(n*NHEAD + h)*NCH + c) * 4096;
#pragma unroll
    for (int j = 0; j < 16; ++j) Mpart[base + (size_t)dk*64 + dv0 + j] = acc[j];
    if (tid < 64) Upart[((size_t)(n*NHEAD + h)*NCH + c)*64 + tid] = uacc;
}

// ---------------- MFMA chunk attention (prefix folded in from Mpart/Upart) ----------------
__global__ __launch_bounds__(512) void k_cattend(
        const unsigned short* __restrict__ QKVb, const float* __restrict__ Mpart,
        const float* __restrict__ Upart, unsigned short* __restrict__ Ab) {
    int b = blockIdx.x;
    int c = b % NCH, h = (b / NCH) % NHEAD, n = b / (NCH * NHEAD);
    int nh = n*NHEAD + h;
    int tid = threadIdx.x;
    int wid = tid >> 6, lane = tid & 63;
    int l15 = lane & 15, lg = lane >> 4;
    __shared__ __align__(16) unsigned short Vt[64*200];   // [vd][j] j=0..191 (V | P)
    __shared__ __align__(16) unsigned short St[11264];
    __shared__ float wf[64];
    int rowbase = n*SEQL + c*CHUNK;

    {
        int j = tid & 127, vd0 = (tid >> 7) * 16;
        const unsigned short* vp = QKVb + (size_t)(rowbase + j)*QSTR + 1024 + h*64 + vd0;
        uint4 u0 = *(const uint4*)vp;
        uint4 u1 = *(const uint4*)(vp + 8);
        const unsigned short* e0 = (const unsigned short*)&u0;
        const unsigned short* e1 = (const unsigned short*)&u1;
#pragma unroll
        for (int t = 0; t < 8; ++t) Vt[(vd0 + t)*200 + j] = e0[t];
#pragma unroll
        for (int t = 0; t < 8; ++t) Vt[(vd0 + 8 + t)*200 + j] = e1[t];
    }
    {
        int d = tid & 63, vd0 = (tid >> 6) * 8;
        float pr[8] = {};
        for (int cc = 0; cc < c; ++cc) {
            const float* pp = Mpart + ((size_t)nh*NCH + cc)*4096 + (size_t)d*64 + vd0;
            float4 p0 = *(const float4*)pp;
            float4 p1 = *(const float4*)(pp + 4);
            pr[0]+=p0.x; pr[1]+=p0.y; pr[2]+=p0.z; pr[3]+=p0.w;
            pr[4]+=p1.x; pr[5]+=p1.y; pr[6]+=p1.z; pr[7]+=p1.w;
        }
#pragma unroll
        for (int t = 0; t < 8; ++t) Vt[(vd0 + t)*200 + 128 + d] = f2bf(pr[t]);
    }
    if (tid < 64) {
        float u = 0.f;
        for (int cc = 0; cc < c; ++cc) u += Upart[((size_t)nh*NCH + cc)*64 + tid];
        wf[tid] = u;
    }

    int r0 = wid * 16;
    int koff = lg * 8;
    const unsigned short* qp = QKVb + (size_t)(rowbase + r0 + l15)*QSTR + h*64 + koff;
    uint4 uq0 = *(const uint4*)qp;
    uint4 uq1 = *(const uint4*)(qp + 32);
    bf16x8 aq0 = *(bf16x8*)&uq0;
    bf16x8 aq1 = *(bf16x8*)&uq1;

    int nact = (wid & ~1) + 2;
    int sstr_ = 32*((wid >> 1) + 1) + 8;
    int p_ = wid >> 1;
    int sig = p_*(p_+1) + (wid & 1)*(p_+1);
    int stoff_ = 128*wid + 512*sig;

    float rsum[4] = {0.f, 0.f, 0.f, 0.f};
    for (int nt = 0; nt < nact; ++nt) {
        int j0 = nt*16;
        const unsigned short* kp = QKVb + (size_t)(rowbase + j0 + l15)*QSTR + 512 + h*64 + koff;
        uint4 uk0 = *(const uint4*)kp;
        uint4 uk1 = *(const uint4*)(kp + 32);
        f32x4 s = {0.f, 0.f, 0.f, 0.f};
        s = __builtin_amdgcn_mfma_f32_16x16x32_bf16(aq0, *(bf16x8*)&uk0, s, 0, 0, 0);
        s = __builtin_amdgcn_mfma_f32_16x16x32_bf16(aq1, *(bf16x8*)&uk1, s, 0, 0, 0);
        int jcol = j0 + l15;
#pragma unroll
        for (int r = 0; r < 4; ++r) {
            int irow = r0 + lg*4 + r;
            float sv = (jcol <= irow) ? s[r] : 0.f;
            rsum[r] += sv;
            St[stoff_ + (lg*4 + r)*sstr_ + jcol] = f2bf(sv);
        }
    }
    __syncthreads();

    float qw = 0.f;
    const unsigned short* q0e = (const unsigned short*)&uq0;
    const unsigned short* q1e = (const unsigned short*)&uq1;
#pragma unroll
    for (int jj = 0; jj < 8; ++jj) {
        qw += bf2f(q0e[jj]) * wf[koff + jj];
        qw += bf2f(q1e[jj]) * wf[32 + koff + jj];
    }
    qw += __shfl_xor(qw, 16);
    qw += __shfl_xor(qw, 32);

    f32x4 o[4] = {};
    int nkr = (wid >> 1) + 1;
    for (int ks = 0; ks < nkr; ++ks) {
        bf16x8 as = *(bf16x8*)&St[stoff_ + l15*sstr_ + ks*32 + koff];
#pragma unroll
        for (int nt = 0; nt < 4; ++nt) {
            bf16x8 bv = *(bf16x8*)&Vt[(nt*16 + l15)*200 + ks*32 + koff];
            o[nt] = __builtin_amdgcn_mfma_f32_16x16x32_bf16(as, bv, o[nt], 0, 0, 0);
        }
    }
#pragma unroll
    for (int kk = 0; kk < 2; ++kk) {
        bf16x8 as = kk ? aq1 : aq0;
#pragma unroll
        for (int nt = 0; nt < 4; ++nt) {
            bf16x8 bv = *(bf16x8*)&Vt[(nt*16 + l15)*200 + 128 + kk*32 + koff];
            o[nt] = __builtin_amdgcn_mfma_f32_16x16x32_bf16(as, bv, o[nt], 0, 0, 0);
        }
    }

#pragma unroll
    for (int r = 0; r < 4; ++r) {
        float v = rsum[r];
        v += __shfl_xor(v, 1); v += __shfl_xor(v, 2);
        v += __shfl_xor(v, 4); v += __shfl_xor(v, 8);
        rsum[r] = v;
    }
#pragma unroll
    for (int r = 0; r < 4; ++r) {
        float qwr = __shfl(qw, lg*4 + r);
        float z = 1.f / (rsum[r] + qwr + ATT_EPS_F);
        int orow = rowbase + r0 + lg*4 + r;
        unsigned short* op = Ab + (size_t)orow*EMB + h*64 + l15;
#pragma unroll
        for (int nt = 0; nt < 4; ++nt)
            op[nt*16] = f2bf(o[nt][r] * z);
    }
}

// ---------------- residual (nsl slices) + LayerNorm -> fp32 Y and bf16 Yb ----------------
__global__ __launch_bounds__(256) void k_ln(
        const float* __restrict__ X, const float* __restrict__ R, int nsl,
        const float* __restrict__ g, const float* __restrict__ bb,
        float* __restrict__ Y, unsigned short* __restrict__ Yb) {
    int row = blockIdx.x, tid = threadIdx.x;
    float2 v = *(const float2*)(X + (size_t)row*EMB + tid*2);
    for (int z = 0; z < nsl; ++z) {
        float2 r = *(const float2*)(R + (size_t)z*1048576 + (size_t)row*EMB + tid*2);
        v.x += r.x; v.y += r.y;
    }
    float s = v.x + v.y, ss = v.x*v.x + v.y*v.y;
#pragma unroll
    for (int off = 32; off; off >>= 1) {
        s  += __shfl_down(s, off);
        ss += __shfl_down(ss, off);
    }
    __shared__ float sb[4], ssb[4];
    int wid = tid >> 6, lane = tid & 63;
    if (!lane) { sb[wid] = s; ssb[wid] = ss; }
    __syncthreads();
    float tot  = sb[0] + sb[1] + sb[2] + sb[3];
    float tots = ssb[0] + ssb[1] + ssb[2] + ssb[3];
    float mean = tot * (1.f/EMB);
    float var  = tots * (1.f/EMB) - mean*mean;
    float inv  = rsqrtf(var + LN_EPS_F);
    int e = tid*2;
    float2 o;
    o.x = (v.x - mean)*inv*g[e]   + bb[e];
    o.y = (v.y - mean)*inv*g[e+1] + bb[e+1];
    *(float2*)(Y + (size_t)row*EMB + e) = o;
    ushort2 ob; ob.x = f2bf(o.x); ob.y = f2bf(o.y);
    *(ushort2*)(Yb + (size_t)row*EMB + e) = ob;
}

// ---------------- fused final LN + head (512->17), 8 rows/block ----------------
__global__ __launch_bounds__(256) void k_lnhead(
        const float* __restrict__ X, const float* __restrict__ g, const float* __restrict__ bb,
        const float* __restrict__ Wh, float* __restrict__ out) {
    __shared__ float ys[8][512];
    __shared__ float whs[512*17];
    int tid = threadIdx.x;
    for (int i = tid; i < 512*17; i += 256) whs[i] = Wh[i];

    int row = tid >> 5, l32 = tid & 31;
    int rg = blockIdx.x * 8 + row;
    const float* xr = X + (size_t)rg*EMB + l32*16;
    float v[16];
    float s = 0.f, ss = 0.f;
#pragma unroll
    for (int i = 0; i < 4; ++i) {
        float4 a = *(const float4*)(xr + i*4);
        v[i*4+0]=a.x; v[i*4+1]=a.y; v[i*4+2]=a.z; v[i*4+3]=a.w;
        s += a.x+a.y+a.z+a.w;
        ss += a.x*a.x+a.y*a.y+a.z*a.z+a.w*a.w;
    }
#pragma unroll
    for (int off = 1; off < 32; off <<= 1) { s += __shfl_xor(s, off); ss += __shfl_xor(ss, off); }
    float mean = s * (1.f/EMB);
    float var  = ss * (1.f/EMB) - mean*mean;
    float inv  = rsqrtf(var + LN_EPS_F);
    int c0 = l32*16;
#pragma unroll
    for (int i = 0; i < 16; ++i) {
        float y = (v[i] - mean)*inv*g[c0+i] + bb[c0+i];
        ys[row][c0+i] = y;
    }
    __syncthreads();

    float part[17];
#pragma unroll
    for (int cc = 0; cc < 17; ++cc) part[cc] = 0.f;
    for (int kk = 0; kk < 16; ++kk) {
        int k = c0 + kk;
        float yv = ys[row][k];
#pragma unroll
        for (int cc = 0; cc < 17; ++cc) part[cc] += yv * whs[k*17 + cc];
    }
#pragma unroll
    for (int cc = 0; cc < 17; ++cc) {
        float pv = part[cc];
#pragma unroll
        for (int off = 1; off < 32; off <<= 1) pv += __shfl_xor(pv, off);
        if (l32 == 0) out[(size_t)rg*17 + cc] = pv;
    }
}

extern "C" void kernel_launch(void* const* d_in, const int* in_sizes, int n_in,
                              void* d_out, int out_size, void* d_ws, size_t ws_size,
                              hipStream_t stream) {
    (void)in_sizes; (void)n_in; (void)out_size; (void)ws_size;
    const int*   value = (const int*)d_in[0];
    const int*   depth = (const int*)d_in[1];
    const int*   pos   = (const int*)d_in[2];
    const float* sos   = (const float*)d_in[3];
    const float* tok   = (const float*)d_in[4];
    const float* dep   = (const float*)d_in[5];
    const float* spa   = (const float*)d_in[6];
    const float* Wq0   = (const float*)d_in[7];
    const float* Wk0   = (const float*)d_in[8];
    const float* Wv0   = (const float*)d_in[9];
    const float* Wo0   = (const float*)d_in[10];
    const float* bq0   = (const float*)d_in[11];
    const float* bk0   = (const float*)d_in[12];
    const float* bv0   = (const float*)d_in[13];
    const float* bo0   = (const float*)d_in[14];
    const float* ln1g  = (const float*)d_in[15];
    const float* ln1b  = (const float*)d_in[16];
    const float* ln2g  = (const float*)d_in[17];
    const float* ln2b  = (const float*)d_in[18];
    const float* W10   = (const float*)d_in[19];
    const float* b10   = (const float*)d_in[20];
    const float* W20   = (const float*)d_in[21];
    const float* b20   = (const float*)d_in[22];
    const float* lnfg  = (const float*)d_in[23];
    const float* lnfb  = (const float*)d_in[24];
    const float* Wh    = (const float*)d_in[25];
    float* out = (float*)d_out;
    float* ws  = (float*)d_ws;

    float*          X     = ws;                                  // 1048576 f
    unsigned short* Xb    = (unsigned short*)(ws + 1048576);     // 524288 f
    unsigned short* QKVb  = (unsigned short*)(ws + 1572864);     // 1572864 f
    unsigned short* Ab    = (unsigned short*)(ws + 3145728);     // 524288 f
    unsigned short* Hb    = (unsigned short*)(ws + 1572864);     // alias QKVb+Ab (2048x2048 bf16)
    float*          Mpart = ws + 3670016;                        // 524288 f
    float*          Upart = ws + 4194304;                        // 8192 f
    float*          AO    = ws + 4202496;                        // 4 x 1048576 f (split-K slices)
    float*          bqkv  = ws + 8396800;                        // 6144 f
    unsigned short* wAll  = (unsigned short*)(ws + 8402944);     // 4 x 3145728 sh

    k_embed<<<NROWS, 128, 0, stream>>>(value, depth, pos, sos, tok, dep, spa, X, Xb);
    k_wconv<<<6168, 256, 0, stream>>>(Wq0, Wk0, Wv0, Wo0, W10, W20, bq0, bk0, bv0, wAll, bqkv);

    for (int L = 0; L < NLAYER; ++L) {
        unsigned short* lay  = wAll + (size_t)L*3145728;
        unsigned short* qkvT = lay;
        unsigned short* woT  = lay + 786432;
        unsigned short* w1T  = lay + 1048576;
        unsigned short* w2T  = lay + 2097152;

        // QKV: 32x128 tiles, 2 waves -> 12x64 = 768 blocks
        k_mgemm<32,128,1,2,4,1><<<dim3(12,64), 128, 0, stream>>>(
            Xb, qkvT, bqkv + L*1536, value, nullptr, QKVb, 1536, 512, 512, 1536);

        k_cpart<<<NBATCH*NHEAD*NCH, 256, 0, stream>>>(QKVb, Mpart, Upart);
        k_cattend<<<NBATCH*NHEAD*NCH, 512, 0, stream>>>(QKVb, Mpart, Upart, Ab);

        // Wo: 32x128, split-K=2 -> 4x64x2 = 512 blocks, 8 K-steps
        k_mgemm<32,128,1,2,0,2><<<dim3(4,64,2), 128, 0, stream>>>(
            Ab, woT, bo0 + (size_t)L*EMB, nullptr, AO, nullptr, 512, 512, 512, 512);
        k_ln<<<NROWS, 256, 0, stream>>>(X, AO, 2, ln1g + (size_t)L*EMB, ln1b + (size_t)L*EMB, X, Xb);

        // FF1: 32x128 -> 16x64 = 1024 blocks
        k_mgemm<32,128,1,2,3,1><<<dim3(16,64), 128, 0, stream>>>(
            Xb, w1T, b10 + (size_t)L*FFDIM, nullptr, nullptr, Hb, 2048, 512, 512, 2048);

        // FF2: 32x128, split-K=4 -> 4x64x4 = 1024 blocks, 16 K-steps
        k_mgemm<32,128,1,2,0,4><<<dim3(4,64,4), 128, 0, stream>>>(
            Hb, w2T, b20 + (size_t)L*EMB, nullptr, AO, nullptr, 512, 2048, 2048, 512);
        k_ln<<<NROWS, 256, 0, stream>>>(X, AO, 4, ln2g + (size_t)L*EMB, ln2b + (size_t)L*EMB, X, Xb);
    }
    k_lnhead<<<NROWS/8, 256, 0, stream>>>(X, lnfg, lnfb, Wh, out);
}

// Round 8
// 430.637 us; speedup vs baseline: 1.0282x; 1.0282x over previous
//
#include <hip/hip_runtime.h>
#include <math.h>

#define EMB 512
#define SEQL 1024
#define NBATCH 2
#define NHEAD 8
#define FFDIM 2048
#define NLAYER 4
#define NROWS (NBATCH*SEQL)
#define CHUNK 128
#define NCH (SEQL/CHUNK)
#define QSTR 1536
#define LN_EPS_F 1e-5f
#define ATT_EPS_F 1e-6f

typedef __bf16 bf16x8 __attribute__((ext_vector_type(8)));
typedef float f32x4 __attribute__((ext_vector_type(4)));

__device__ __forceinline__ unsigned short f2bf(float f) {
    unsigned int u = __float_as_uint(f);
    u += 0x7FFFu + ((u >> 16) & 1u);
    return (unsigned short)(u >> 16);
}
__device__ __forceinline__ float bf2f(unsigned short x) {
    return __uint_as_float(((unsigned int)x) << 16);
}
__device__ __forceinline__ void gl_lds16(const unsigned short* g, unsigned short* l) {
    __builtin_amdgcn_global_load_lds(
        (__attribute__((address_space(1))) void*)const_cast<unsigned short*>(g),
        (__attribute__((address_space(3))) void*)l, 16, 0, 0);
}

// ---------------- embedding + shift-right(SOS), writes fp32 X and bf16 Xb ----------------
__global__ void k_embed(const int* __restrict__ value, const int* __restrict__ depth,
                        const int* __restrict__ pos, const float* __restrict__ sos,
                        const float* __restrict__ tok, const float* __restrict__ dep,
                        const float* __restrict__ spa, float* __restrict__ X,
                        unsigned short* __restrict__ Xb) {
    int row = blockIdx.x;
    int n = row / SEQL, s = row % SEQL;
    int e = threadIdx.x * 4;
    float4 o;
    if (s == 0) {
        o = *(const float4*)(sos + e);
    } else {
        int sp = s - 1;
        int tv = value[n*SEQL + sp];
        int dv = depth[n*SEQL + sp];
        float4 a = *(const float4*)(tok + (size_t)tv*EMB + e);
        float4 b = *(const float4*)(dep + (size_t)dv*EMB + e);
        o.x = a.x+b.x; o.y = a.y+b.y; o.z = a.z+b.z; o.w = a.w+b.w;
#pragma unroll
        for (int ax = 0; ax < 3; ++ax) {
            int p = pos[((size_t)ax*NBATCH + n)*SEQL + sp];
            float4 c = *(const float4*)(spa + ((size_t)ax*257 + p)*EMB + e);
            o.x += c.x; o.y += c.y; o.z += c.z; o.w += c.w;
        }
    }
    *(float4*)(X + (size_t)row*EMB + e) = o;
    ushort4 ob; ob.x = f2bf(o.x); ob.y = f2bf(o.y); ob.z = f2bf(o.z); ob.w = f2bf(o.w);
    *(ushort4*)(Xb + (size_t)row*EMB + e) = ob;
}

// ---------------- weight convert, ALL layers + qkv bias pack, one launch ----------------
__global__ __launch_bounds__(256) void k_wconv(
        const float* __restrict__ Wq0, const float* __restrict__ Wk0, const float* __restrict__ Wv0,
        const float* __restrict__ Wo0, const float* __restrict__ W10, const float* __restrict__ W20,
        const float* __restrict__ bq0, const float* __restrict__ bk0, const float* __restrict__ bv0,
        unsigned short* __restrict__ wAll, float* __restrict__ bqkv) {
    int idx = blockIdx.x*256 + threadIdx.x;
    if (idx >= 1572864) {
        int t = idx - 1572864;
        if (t < 6144) {
            int L = t / 1536, c = t % 1536;
            float v = (c < 512) ? bq0[L*512 + c] : (c < 1024) ? bk0[L*512 + c - 512] : bv0[L*512 + c - 1024];
            bqkv[L*1536 + c] = v;
        }
        return;
    }
    int L = idx / 393216;
    int t0 = idx % 393216;
    const float* Wq = Wq0 + (size_t)L*EMB*EMB;
    const float* Wk = Wk0 + (size_t)L*EMB*EMB;
    const float* Wv = Wv0 + (size_t)L*EMB*EMB;
    const float* Wo = Wo0 + (size_t)L*EMB*EMB;
    const float* W1 = W10 + (size_t)L*EMB*FFDIM;
    const float* W2 = W20 + (size_t)L*FFDIM*EMB;
    unsigned short* lay = wAll + (size_t)L*3145728;
    unsigned short* qkvT = lay;
    unsigned short* woT  = lay + 786432;
    unsigned short* w1T  = lay + 1048576;
    unsigned short* w2T  = lay + 2097152;

    const float* src; unsigned short* dst; size_t soff; size_t doff;
    if (t0 < 131072) {
        int sub = t0 >> 15, t = t0 & 32767;
        int kb = t >> 9, n = t & 511;
        src = (sub == 0) ? Wq : (sub == 1) ? Wk : (sub == 2) ? Wv : Wo;
        soff = (size_t)kb*8*512 + n;
        if (sub < 3) { dst = qkvT; doff = ((size_t)kb*1536 + sub*512 + n)*8; }
        else         { dst = woT;  doff = ((size_t)kb*512 + n)*8; }
        unsigned int p[4];
#pragma unroll
        for (int t2 = 0; t2 < 4; ++t2) {
            unsigned int lo = f2bf(src[soff + (size_t)(2*t2)*512]);
            unsigned int hi = f2bf(src[soff + (size_t)(2*t2+1)*512]);
            p[t2] = lo | (hi << 16);
        }
        *(uint4*)(dst + doff) = make_uint4(p[0], p[1], p[2], p[3]);
    } else if (t0 < 262144) {
        int t = t0 - 131072;
        int kb = t >> 11, n = t & 2047;
        soff = (size_t)kb*8*2048 + n;
        doff = ((size_t)kb*2048 + n)*8;
        unsigned int p[4];
#pragma unroll
        for (int t2 = 0; t2 < 4; ++t2) {
            unsigned int lo = f2bf(W1[soff + (size_t)(2*t2)*2048]);
            unsigned int hi = f2bf(W1[soff + (size_t)(2*t2+1)*2048]);
            p[t2] = lo | (hi << 16);
        }
        *(uint4*)(w1T + doff) = make_uint4(p[0], p[1], p[2], p[3]);
    } else {
        int t = t0 - 262144;
        int kb = t >> 9, n = t & 511;
        soff = (size_t)kb*8*512 + n;
        doff = ((size_t)kb*512 + n)*8;
        unsigned int p[4];
#pragma unroll
        for (int t2 = 0; t2 < 4; ++t2) {
            unsigned int lo = f2bf(W2[soff + (size_t)(2*t2)*512]);
            unsigned int hi = f2bf(W2[soff + (size_t)(2*t2+1)*512]);
            p[t2] = lo | (hi << 16);
        }
        *(uint4*)(w2T + doff) = make_uint4(p[0], p[1], p[2], p[3]);
    }
}

// ---------------- bf16 MFMA GEMM, WR x WC waves, optional split-K ----------------
// ACT: 0 = none -> fp32 Cf (+ z*1048576 per k-slice, bias only on slice 0)
//      3 = gelu -> bf16 Cb ; 4 = fused QKV epilogue -> bf16 Cb
template<int BM, int BN, int WR, int WC, int ACT, int KS>
__global__ __launch_bounds__(WR*WC*64) void k_mgemm(
        const unsigned short* __restrict__ A, const unsigned short* __restrict__ Wt,
        const float* __restrict__ bias, const int* __restrict__ maskv,
        float* __restrict__ Cf, unsigned short* __restrict__ Cb,
        int N, int K, int lda, int ldc) {
    constexpr int THREADS = WR*WC*64;
    constexpr int WM = BM/WR, WN = BN/WC;
    constexpr int FM = WM/16, FN = WN/16;
    __shared__ __align__(16) unsigned short As[BM*32];
    __shared__ __align__(16) unsigned short Bs[BN*32];
    int tid = threadIdx.x;
    int lane = tid & 63;
    int l15 = lane & 15, lg = lane >> 4;
    int wid = tid >> 6;
    int wm = (wid / WC) * WM, wn = (wid % WC) * WN;
    int bm = blockIdx.y * BM, bn = blockIdx.x * BN;
    int kz = blockIdx.z;
    int ksl = K / KS;
    int kbeg = kz * ksl, kend = kbeg + ksl;

    f32x4 acc[FM][FN] = {};

    int a_off = (wm + l15)*32 + lg*8;
    int b_off = lg*BN*8 + (wn + l15)*8;

    for (int k0 = kbeg; k0 < kend; k0 += 32) {
#pragma unroll
        for (int i = 0; i < BM*4/THREADS; ++i) {
            int s = tid + i*THREADS;
            int m = s >> 2, kq = s & 3;
            gl_lds16(A + (size_t)(bm + m)*lda + k0 + kq*8, &As[s*8]);
        }
#pragma unroll
        for (int i = 0; i < BN*4/THREADS; ++i) {
            int s = tid + i*THREADS;
            int kb = s / BN, n = s - kb*BN;
            gl_lds16(Wt + ((size_t)(k0/8 + kb)*N + bn + n)*8, &Bs[s*8]);
        }
        __syncthreads();
        bf16x8 af[FM], bfr[FN];
#pragma unroll
        for (int mi = 0; mi < FM; ++mi) af[mi] = *(const bf16x8*)&As[a_off + mi*512];
#pragma unroll
        for (int ni = 0; ni < FN; ++ni) bfr[ni] = *(const bf16x8*)&Bs[b_off + ni*128];
#pragma unroll
        for (int mi = 0; mi < FM; ++mi)
#pragma unroll
            for (int ni = 0; ni < FN; ++ni)
                acc[mi][ni] = __builtin_amdgcn_mfma_f32_16x16x32_bf16(af[mi], bfr[ni], acc[mi][ni], 0, 0, 0);
        __syncthreads();
    }

    int r0 = bm + wm + lg*4;
    int c0 = bn + wn + l15;
    float* Cfz = Cf + (size_t)kz * 1048576;
#pragma unroll
    for (int mi = 0; mi < FM; ++mi) {
#pragma unroll
        for (int ni = 0; ni < FN; ++ni) {
            int col = c0 + ni*16;
#pragma unroll
            for (int j = 0; j < 4; ++j) {
                int row = r0 + mi*16 + j;
                float c = acc[mi][ni][j];
                if (KS == 1 || kz == 0) c += bias[col];
                if (ACT == 4) {
                    int reg = col >> 9;
                    if (reg == 0) { c = (c > 0.f) ? c + 1.f : expf(c); }
                    else if (reg == 1) { c = (c > 0.f) ? c + 1.f : expf(c); c *= (maskv[row] != 0) ? 1.f : 0.f; }
                    Cb[(size_t)row*ldc + col] = f2bf(c);
                } else if (ACT == 3) {
                    c = 0.5f * c * (1.f + erff(c * 0.70710678118654752f));
                    Cb[(size_t)row*ldc + col] = f2bf(c);
                } else {
                    Cfz[(size_t)row*ldc + col] = c;
                }
            }
        }
    }
}

// ---------------- per-HALF-chunk partial K^T V (64x64) and sum(k), bf16 in ----------------
// block b = ((n*NHEAD+h)*NCH + c)*2 + half ; 64 rows each -> 256 blocks
__global__ __launch_bounds__(256) void k_cpart(
        const unsigned short* __restrict__ QKVb, float* __restrict__ Mpart, float* __restrict__ Upart) {
    int b = blockIdx.x;
    int half = b & 1;
    int cidx = b >> 1;
    int c = cidx % NCH;
    int nh = cidx / NCH;
    int h = nh % NHEAD, n = nh / NHEAD;
    const unsigned short* Kp = QKVb + (size_t)(n*SEQL + c*CHUNK + half*64)*QSTR + 512 + h*64;
    const unsigned short* Vp = Kp + 512;
    __shared__ float Ks[8][64], Vs[8][64];
    int tid = threadIdx.x;
    int dk = tid >> 2, dv0 = (tid & 3) * 16;
    int lr = tid >> 5, lc = (tid & 31) * 2;
    float acc[16] = {};
    float uacc = 0.f;
    for (int s0 = 0; s0 < 64; s0 += 8) {
        ushort2 k2 = *(const ushort2*)(Kp + (size_t)(s0 + lr)*QSTR + lc);
        ushort2 v2 = *(const ushort2*)(Vp + (size_t)(s0 + lr)*QSTR + lc);
        Ks[lr][lc] = bf2f(k2.x); Ks[lr][lc+1] = bf2f(k2.y);
        Vs[lr][lc] = bf2f(v2.x); Vs[lr][lc+1] = bf2f(v2.y);
        __syncthreads();
#pragma unroll
        for (int ss = 0; ss < 8; ++ss) {
            float kk = Ks[ss][dk];
#pragma unroll
            for (int j = 0; j < 16; ++j) acc[j] += kk * Vs[ss][dv0 + j];
        }
        if (tid < 64) {
#pragma unroll
            for (int ss = 0; ss < 8; ++ss) uacc += Ks[ss][tid];
        }
        __syncthreads();
    }
    size_t base = (size_t)b * 4096;
#pragma unroll
    for (int j = 0; j < 16; ++j) Mpart[base + (size_t)dk*64 + dv0 + j] = acc[j];
    if (tid < 64) Upart[(size_t)b*64 + tid] = uacc;
}

// ---------------- MFMA chunk attention, 256 threads, 64 q-rows per block ----------------
// block b = ((n*NHEAD+h)*NCH + c)*2 + grp ; wave w handles wid = 4*grp + w
__global__ __launch_bounds__(256) void k_cattend(
        const unsigned short* __restrict__ QKVb, const float* __restrict__ Mpart,
        const float* __restrict__ Upart, unsigned short* __restrict__ Ab) {
    int b = blockIdx.x;
    int grp = b & 1;
    int cidx = b >> 1;
    int c = cidx % NCH;
    int nh = cidx / NCH;
    int h = nh % NHEAD, n = nh / NHEAD;
    int tid = threadIdx.x;
    int wid = (grp << 2) + (tid >> 6);
    int lane = tid & 63;
    int l15 = lane & 15, lg = lane >> 4;
    __shared__ __align__(16) unsigned short Vt[64*200];   // [vd][j] j=0..191 (V | P)
    __shared__ __align__(16) unsigned short St[11264];
    __shared__ float wf[64];
    int rowbase = n*SEQL + c*CHUNK;

    // ---- stage Vt: j<128 = V[j][vd] (full chunk) ----
    {
        int j = tid & 127;
        const unsigned short* vp = QKVb + (size_t)(rowbase + j)*QSTR + 1024 + h*64;
#pragma unroll
        for (int vh = 0; vh < 2; ++vh) {
            int vd0 = (tid >> 7) * 16 + vh * 32;
            uint4 u0 = *(const uint4*)(vp + vd0);
            uint4 u1 = *(const uint4*)(vp + vd0 + 8);
            const unsigned short* e0 = (const unsigned short*)&u0;
            const unsigned short* e1 = (const unsigned short*)&u1;
#pragma unroll
            for (int t = 0; t < 8; ++t) Vt[(vd0 + t)*200 + j] = e0[t];
#pragma unroll
            for (int t = 0; t < 8; ++t) Vt[(vd0 + 8 + t)*200 + j] = e1[t];
        }
    }
    // ---- prefix P: sum of the 2c half-chunk parts -> Vt cols 128..191 ----
    {
        int d = tid & 63;
#pragma unroll
        for (int ph = 0; ph < 2; ++ph) {
            int vd0 = (tid >> 6) * 8 + ph * 32;
            float pr[8] = {};
            for (int p = 0; p < 2*c; ++p) {
                const float* pp = Mpart + ((size_t)nh*NCH*2 + p)*4096 + (size_t)d*64 + vd0;
                float4 p0 = *(const float4*)pp;
                float4 p1 = *(const float4*)(pp + 4);
                pr[0]+=p0.x; pr[1]+=p0.y; pr[2]+=p0.z; pr[3]+=p0.w;
                pr[4]+=p1.x; pr[5]+=p1.y; pr[6]+=p1.z; pr[7]+=p1.w;
            }
#pragma unroll
            for (int t = 0; t < 8; ++t) Vt[(vd0 + t)*200 + 128 + d] = f2bf(pr[t]);
        }
    }
    if (tid < 64) {
        float u = 0.f;
        for (int p = 0; p < 2*c; ++p) u += Upart[((size_t)nh*NCH*2 + p)*64 + tid];
        wf[tid] = u;
    }

    // ---- stage 1: S = Q K^T ----
    int r0 = wid * 16;
    int koff = lg * 8;
    const unsigned short* qp = QKVb + (size_t)(rowbase + r0 + l15)*QSTR + h*64 + koff;
    uint4 uq0 = *(const uint4*)qp;
    uint4 uq1 = *(const uint4*)(qp + 32);
    bf16x8 aq0 = *(bf16x8*)&uq0;
    bf16x8 aq1 = *(bf16x8*)&uq1;

    int nact = (wid & ~1) + 2;
    int sstr_ = 32*((wid >> 1) + 1) + 8;
    int p_ = wid >> 1;
    int sig = p_*(p_+1) + (wid & 1)*(p_+1);
    int stoff_ = 128*wid + 512*sig;

    float rsum[4] = {0.f, 0.f, 0.f, 0.f};
    for (int nt = 0; nt < nact; ++nt) {
        int j0 = nt*16;
        const unsigned short* kp = QKVb + (size_t)(rowbase + j0 + l15)*QSTR + 512 + h*64 + koff;
        uint4 uk0 = *(const uint4*)kp;
        uint4 uk1 = *(const uint4*)(kp + 32);
        f32x4 s = {0.f, 0.f, 0.f, 0.f};
        s = __builtin_amdgcn_mfma_f32_16x16x32_bf16(aq0, *(bf16x8*)&uk0, s, 0, 0, 0);
        s = __builtin_amdgcn_mfma_f32_16x16x32_bf16(aq1, *(bf16x8*)&uk1, s, 0, 0, 0);
        int jcol = j0 + l15;
#pragma unroll
        for (int r = 0; r < 4; ++r) {
            int irow = r0 + lg*4 + r;
            float sv = (jcol <= irow) ? s[r] : 0.f;
            rsum[r] += sv;
            St[stoff_ + (lg*4 + r)*sstr_ + jcol] = f2bf(sv);
        }
    }
    __syncthreads();

    // ---- q . w ----
    float qw = 0.f;
    const unsigned short* q0e = (const unsigned short*)&uq0;
    const unsigned short* q1e = (const unsigned short*)&uq1;
#pragma unroll
    for (int jj = 0; jj < 8; ++jj) {
        qw += bf2f(q0e[jj]) * wf[koff + jj];
        qw += bf2f(q1e[jj]) * wf[32 + koff + jj];
    }
    qw += __shfl_xor(qw, 16);
    qw += __shfl_xor(qw, 32);

    // ---- stage 2: O = S @ V_ext ----
    f32x4 o[4] = {};
    int nkr = (wid >> 1) + 1;
    for (int ks = 0; ks < nkr; ++ks) {
        bf16x8 as = *(bf16x8*)&St[stoff_ + l15*sstr_ + ks*32 + koff];
#pragma unroll
        for (int nt = 0; nt < 4; ++nt) {
            bf16x8 bv = *(bf16x8*)&Vt[(nt*16 + l15)*200 + ks*32 + koff];
            o[nt] = __builtin_amdgcn_mfma_f32_16x16x32_bf16(as, bv, o[nt], 0, 0, 0);
        }
    }
#pragma unroll
    for (int kk = 0; kk < 2; ++kk) {
        bf16x8 as = kk ? aq1 : aq0;
#pragma unroll
        for (int nt = 0; nt < 4; ++nt) {
            bf16x8 bv = *(bf16x8*)&Vt[(nt*16 + l15)*200 + 128 + kk*32 + koff];
            o[nt] = __builtin_amdgcn_mfma_f32_16x16x32_bf16(as, bv, o[nt], 0, 0, 0);
        }
    }

#pragma unroll
    for (int r = 0; r < 4; ++r) {
        float v = rsum[r];
        v += __shfl_xor(v, 1); v += __shfl_xor(v, 2);
        v += __shfl_xor(v, 4); v += __shfl_xor(v, 8);
        rsum[r] = v;
    }
#pragma unroll
    for (int r = 0; r < 4; ++r) {
        float qwr = __shfl(qw, lg*4 + r);
        float z = 1.f / (rsum[r] + qwr + ATT_EPS_F);
        int orow = rowbase + r0 + lg*4 + r;
        unsigned short* op = Ab + (size_t)orow*EMB + h*64 + l15;
#pragma unroll
        for (int nt = 0; nt < 4; ++nt)
            op[nt*16] = f2bf(o[nt][r] * z);
    }
}

// ---------------- residual (nsl slices) + LayerNorm -> fp32 Y and bf16 Yb ----------------
__global__ __launch_bounds__(256) void k_ln(
        const float* __restrict__ X, const float* __restrict__ R, int nsl,
        const float* __restrict__ g, const float* __restrict__ bb,
        float* __restrict__ Y, unsigned short* __restrict__ Yb) {
    int row = blockIdx.x, tid = threadIdx.x;
    float2 v = *(const float2*)(X + (size_t)row*EMB + tid*2);
    for (int z = 0; z < nsl; ++z) {
        float2 r = *(const float2*)(R + (size_t)z*1048576 + (size_t)row*EMB + tid*2);
        v.x += r.x; v.y += r.y;
    }
    float s = v.x + v.y, ss = v.x*v.x + v.y*v.y;
#pragma unroll
    for (int off = 32; off; off >>= 1) {
        s  += __shfl_down(s, off);
        ss += __shfl_down(ss, off);
    }
    __shared__ float sb[4], ssb[4];
    int wid = tid >> 6, lane = tid & 63;
    if (!lane) { sb[wid] = s; ssb[wid] = ss; }
    __syncthreads();
    float tot  = sb[0] + sb[1] + sb[2] + sb[3];
    float tots = ssb[0] + ssb[1] + ssb[2] + ssb[3];
    float mean = tot * (1.f/EMB);
    float var  = tots * (1.f/EMB) - mean*mean;
    float inv  = rsqrtf(var + LN_EPS_F);
    int e = tid*2;
    float2 o;
    o.x = (v.x - mean)*inv*g[e]   + bb[e];
    o.y = (v.y - mean)*inv*g[e+1] + bb[e+1];
    *(float2*)(Y + (size_t)row*EMB + e) = o;
    ushort2 ob; ob.x = f2bf(o.x); ob.y = f2bf(o.y);
    *(ushort2*)(Yb + (size_t)row*EMB + e) = ob;
}

// ---------------- fused final LN + head (512->17), 8 rows/block ----------------
__global__ __launch_bounds__(256) void k_lnhead(
        const float* __restrict__ X, const float* __restrict__ g, const float* __restrict__ bb,
        const float* __restrict__ Wh, float* __restrict__ out) {
    __shared__ float ys[8][512];
    __shared__ float whs[512*17];
    int tid = threadIdx.x;
    for (int i = tid; i < 512*17; i += 256) whs[i] = Wh[i];

    int row = tid >> 5, l32 = tid & 31;
    int rg = blockIdx.x * 8 + row;
    const float* xr = X + (size_t)rg*EMB + l32*16;
    float v[16];
    float s = 0.f, ss = 0.f;
#pragma unroll
    for (int i = 0; i < 4; ++i) {
        float4 a = *(const float4*)(xr + i*4);
        v[i*4+0]=a.x; v[i*4+1]=a.y; v[i*4+2]=a.z; v[i*4+3]=a.w;
        s += a.x+a.y+a.z+a.w;
        ss += a.x*a.x+a.y*a.y+a.z*a.z+a.w*a.w;
    }
#pragma unroll
    for (int off = 1; off < 32; off <<= 1) { s += __shfl_xor(s, off); ss += __shfl_xor(ss, off); }
    float mean = s * (1.f/EMB);
    float var  = ss * (1.f/EMB) - mean*mean;
    float inv  = rsqrtf(var + LN_EPS_F);
    int c0 = l32*16;
#pragma unroll
    for (int i = 0; i < 16; ++i) {
        float y = (v[i] - mean)*inv*g[c0+i] + bb[c0+i];
        ys[row][c0+i] = y;
    }
    __syncthreads();

    float part[17];
#pragma unroll
    for (int cc = 0; cc < 17; ++cc) part[cc] = 0.f;
    for (int kk = 0; kk < 16; ++kk) {
        int k = c0 + kk;
        float yv = ys[row][k];
#pragma unroll
        for (int cc = 0; cc < 17; ++cc) part[cc] += yv * whs[k*17 + cc];
    }
#pragma unroll
    for (int cc = 0; cc < 17; ++cc) {
        float pv = part[cc];
#pragma unroll
        for (int off = 1; off < 32; off <<= 1) pv += __shfl_xor(pv, off);
        if (l32 == 0) out[(size_t)rg*17 + cc] = pv;
    }
}

extern "C" void kernel_launch(void* const* d_in, const int* in_sizes, int n_in,
                              void* d_out, int out_size, void* d_ws, size_t ws_size,
                              hipStream_t stream) {
    (void)in_sizes; (void)n_in; (void)out_size; (void)ws_size;
    const int*   value = (const int*)d_in[0];
    const int*   depth = (const int*)d_in[1];
    const int*   pos   = (const int*)d_in[2];
    const float* sos   = (const float*)d_in[3];
    const float* tok   = (const float*)d_in[4];
    const float* dep   = (const float*)d_in[5];
    const float* spa   = (const float*)d_in[6];
    const float* Wq0   = (const float*)d_in[7];
    const float* Wk0   = (const float*)d_in[8];
    const float* Wv0   = (const float*)d_in[9];
    const float* Wo0   = (const float*)d_in[10];
    const float* bq0   = (const float*)d_in[11];
    const float* bk0   = (const float*)d_in[12];
    const float* bv0   = (const float*)d_in[13];
    const float* bo0   = (const float*)d_in[14];
    const float* ln1g  = (const float*)d_in[15];
    const float* ln1b  = (const float*)d_in[16];
    const float* ln2g  = (const float*)d_in[17];
    const float* ln2b  = (const float*)d_in[18];
    const float* W10   = (const float*)d_in[19];
    const float* b10   = (const float*)d_in[20];
    const float* W20   = (const float*)d_in[21];
    const float* b20   = (const float*)d_in[22];
    const float* lnfg  = (const float*)d_in[23];
    const float* lnfb  = (const float*)d_in[24];
    const float* Wh    = (const float*)d_in[25];
    float* out = (float*)d_out;
    float* ws  = (float*)d_ws;

    float*          X     = ws;                                  // 1048576 f
    unsigned short* Xb    = (unsigned short*)(ws + 1048576);     // 524288 f
    unsigned short* QKVb  = (unsigned short*)(ws + 1572864);     // 1572864 f
    unsigned short* Ab    = (unsigned short*)(ws + 3145728);     // 524288 f
    unsigned short* Hb    = (unsigned short*)(ws + 1572864);     // alias QKVb+Ab (2048x2048 bf16)
    float*          Mpart = ws + 3670016;                        // 256 x 4096 = 1048576 f
    float*          Upart = ws + 4718592;                        // 16384 f
    float*          AO    = ws + 4734976;                        // 4 x 1048576 f (split-K slices)
    float*          bqkv  = ws + 8929280;                        // 6144 f
    unsigned short* wAll  = (unsigned short*)(ws + 8935424);     // 4 x 3145728 sh

    k_embed<<<NROWS, 128, 0, stream>>>(value, depth, pos, sos, tok, dep, spa, X, Xb);
    k_wconv<<<6168, 256, 0, stream>>>(Wq0, Wk0, Wv0, Wo0, W10, W20, bq0, bk0, bv0, wAll, bqkv);

    for (int L = 0; L < NLAYER; ++L) {
        unsigned short* lay  = wAll + (size_t)L*3145728;
        unsigned short* qkvT = lay;
        unsigned short* woT  = lay + 786432;
        unsigned short* w1T  = lay + 1048576;
        unsigned short* w2T  = lay + 2097152;

        // QKV: 64x128 tiles -> 12x32 = 384 blocks (r6 config)
        k_mgemm<64,128,2,2,4,1><<<dim3(12,32), 256, 0, stream>>>(
            Xb, qkvT, bqkv + L*1536, value, nullptr, QKVb, 1536, 512, 512, 1536);

        k_cpart<<<NBATCH*NHEAD*NCH*2, 256, 0, stream>>>(QKVb, Mpart, Upart);
        k_cattend<<<NBATCH*NHEAD*NCH*2, 256, 0, stream>>>(QKVb, Mpart, Upart, Ab);

        // Wo: 64x64, split-K=2 -> 8x32x2 = 512 blocks (r6 config)
        k_mgemm<64,64,2,2,0,2><<<dim3(8,32,2), 256, 0, stream>>>(
            Ab, woT, bo0 + (size_t)L*EMB, nullptr, AO, nullptr, 512, 512, 512, 512);
        k_ln<<<NROWS, 256, 0, stream>>>(X, AO, 2, ln1g + (size_t)L*EMB, ln1b + (size_t)L*EMB, X, Xb);

        // FF1: 64x128 tiles -> 16x32 = 512 blocks (r6 config)
        k_mgemm<64,128,2,2,3,1><<<dim3(16,32), 256, 0, stream>>>(
            Xb, w1T, b10 + (size_t)L*FFDIM, nullptr, nullptr, Hb, 2048, 512, 512, 2048);

        // FF2: 64x64, split-K=4 -> 8x32x4 = 1024 blocks (r6 config)
        k_mgemm<64,64,2,2,0,4><<<dim3(8,32,4), 256, 0, stream>>>(
            Hb, w2T, b20 + (size_t)L*EMB, nullptr, AO, nullptr, 512, 2048, 2048, 512);
        k_ln<<<NROWS, 256, 0, stream>>>(X, AO, 4, ln2g + (size_t)L*EMB, ln2b + (size_t)L*EMB, X, Xb);
    }
    k_lnhead<<<NROWS/8, 256, 0, stream>>>(X, lnfg, lnfb, Wh, out);
}

// Round 9
// 417.949 us; speedup vs baseline: 1.0594x; 1.0304x over previous
//
#include <hip/hip_runtime.h>
#include <math.h>

#define EMB 512
#define SEQL 1024
#define NBATCH 2
#define NHEAD 8
#define FFDIM 2048
#define NLAYER 4
#define NROWS (NBATCH*SEQL)
#define CHUNK 128
#define NCH (SEQL/CHUNK)
#define QSTR 1536
#define LN_EPS_F 1e-5f
#define ATT_EPS_F 1e-6f

typedef __bf16 bf16x8 __attribute__((ext_vector_type(8)));
typedef float f32x4 __attribute__((ext_vector_type(4)));

__device__ __forceinline__ unsigned short f2bf(float f) {
    unsigned int u = __float_as_uint(f);
    u += 0x7FFFu + ((u >> 16) & 1u);
    return (unsigned short)(u >> 16);
}
__device__ __forceinline__ float bf2f(unsigned short x) {
    return __uint_as_float(((unsigned int)x) << 16);
}
__device__ __forceinline__ void gl_lds16(const unsigned short* g, unsigned short* l) {
    __builtin_amdgcn_global_load_lds(
        (__attribute__((address_space(1))) void*)const_cast<unsigned short*>(g),
        (__attribute__((address_space(3))) void*)l, 16, 0, 0);
}
template<int N_> __device__ __forceinline__ void wait_vm() {
    if constexpr (N_ == 0) asm volatile("s_waitcnt vmcnt(0)" ::: "memory");
    else if constexpr (N_ == 2) asm volatile("s_waitcnt vmcnt(2)" ::: "memory");
    else if constexpr (N_ == 3) asm volatile("s_waitcnt vmcnt(3)" ::: "memory");
    else if constexpr (N_ == 4) asm volatile("s_waitcnt vmcnt(4)" ::: "memory");
    else if constexpr (N_ == 6) asm volatile("s_waitcnt vmcnt(6)" ::: "memory");
}

// ---------------- embedding + shift-right(SOS), writes fp32 X and bf16 Xb ----------------
__global__ void k_embed(const int* __restrict__ value, const int* __restrict__ depth,
                        const int* __restrict__ pos, const float* __restrict__ sos,
                        const float* __restrict__ tok, const float* __restrict__ dep,
                        const float* __restrict__ spa, float* __restrict__ X,
                        unsigned short* __restrict__ Xb) {
    int row = blockIdx.x;
    int n = row / SEQL, s = row % SEQL;
    int e = threadIdx.x * 4;
    float4 o;
    if (s == 0) {
        o = *(const float4*)(sos + e);
    } else {
        int sp = s - 1;
        int tv = value[n*SEQL + sp];
        int dv = depth[n*SEQL + sp];
        float4 a = *(const float4*)(tok + (size_t)tv*EMB + e);
        float4 b = *(const float4*)(dep + (size_t)dv*EMB + e);
        o.x = a.x+b.x; o.y = a.y+b.y; o.z = a.z+b.z; o.w = a.w+b.w;
#pragma unroll
        for (int ax = 0; ax < 3; ++ax) {
            int p = pos[((size_t)ax*NBATCH + n)*SEQL + sp];
            float4 c = *(const float4*)(spa + ((size_t)ax*257 + p)*EMB + e);
            o.x += c.x; o.y += c.y; o.z += c.z; o.w += c.w;
        }
    }
    *(float4*)(X + (size_t)row*EMB + e) = o;
    ushort4 ob; ob.x = f2bf(o.x); ob.y = f2bf(o.y); ob.z = f2bf(o.z); ob.w = f2bf(o.w);
    *(ushort4*)(Xb + (size_t)row*EMB + e) = ob;
}

// ---------------- weight convert, ALL layers + qkv bias pack, one launch ----------------
__global__ __launch_bounds__(256) void k_wconv(
        const float* __restrict__ Wq0, const float* __restrict__ Wk0, const float* __restrict__ Wv0,
        const float* __restrict__ Wo0, const float* __restrict__ W10, const float* __restrict__ W20,
        const float* __restrict__ bq0, const float* __restrict__ bk0, const float* __restrict__ bv0,
        unsigned short* __restrict__ wAll, float* __restrict__ bqkv) {
    int idx = blockIdx.x*256 + threadIdx.x;
    if (idx >= 1572864) {
        int t = idx - 1572864;
        if (t < 6144) {
            int L = t / 1536, c = t % 1536;
            float v = (c < 512) ? bq0[L*512 + c] : (c < 1024) ? bk0[L*512 + c - 512] : bv0[L*512 + c - 1024];
            bqkv[L*1536 + c] = v;
        }
        return;
    }
    int L = idx / 393216;
    int t0 = idx % 393216;
    const float* Wq = Wq0 + (size_t)L*EMB*EMB;
    const float* Wk = Wk0 + (size_t)L*EMB*EMB;
    const float* Wv = Wv0 + (size_t)L*EMB*EMB;
    const float* Wo = Wo0 + (size_t)L*EMB*EMB;
    const float* W1 = W10 + (size_t)L*EMB*FFDIM;
    const float* W2 = W20 + (size_t)L*FFDIM*EMB;
    unsigned short* lay = wAll + (size_t)L*3145728;
    unsigned short* qkvT = lay;
    unsigned short* woT  = lay + 786432;
    unsigned short* w1T  = lay + 1048576;
    unsigned short* w2T  = lay + 2097152;

    const float* src; unsigned short* dst; size_t soff; size_t doff;
    if (t0 < 131072) {
        int sub = t0 >> 15, t = t0 & 32767;
        int kb = t >> 9, n = t & 511;
        src = (sub == 0) ? Wq : (sub == 1) ? Wk : (sub == 2) ? Wv : Wo;
        soff = (size_t)kb*8*512 + n;
        if (sub < 3) { dst = qkvT; doff = ((size_t)kb*1536 + sub*512 + n)*8; }
        else         { dst = woT;  doff = ((size_t)kb*512 + n)*8; }
        unsigned int p[4];
#pragma unroll
        for (int t2 = 0; t2 < 4; ++t2) {
            unsigned int lo = f2bf(src[soff + (size_t)(2*t2)*512]);
            unsigned int hi = f2bf(src[soff + (size_t)(2*t2+1)*512]);
            p[t2] = lo | (hi << 16);
        }
        *(uint4*)(dst + doff) = make_uint4(p[0], p[1], p[2], p[3]);
    } else if (t0 < 262144) {
        int t = t0 - 131072;
        int kb = t >> 11, n = t & 2047;
        soff = (size_t)kb*8*2048 + n;
        doff = ((size_t)kb*2048 + n)*8;
        unsigned int p[4];
#pragma unroll
        for (int t2 = 0; t2 < 4; ++t2) {
            unsigned int lo = f2bf(W1[soff + (size_t)(2*t2)*2048]);
            unsigned int hi = f2bf(W1[soff + (size_t)(2*t2+1)*2048]);
            p[t2] = lo | (hi << 16);
        }
        *(uint4*)(w1T + doff) = make_uint4(p[0], p[1], p[2], p[3]);
    } else {
        int t = t0 - 262144;
        int kb = t >> 9, n = t & 511;
        soff = (size_t)kb*8*512 + n;
        doff = ((size_t)kb*512 + n)*8;
        unsigned int p[4];
#pragma unroll
        for (int t2 = 0; t2 < 4; ++t2) {
            unsigned int lo = f2bf(W2[soff + (size_t)(2*t2)*512]);
            unsigned int hi = f2bf(W2[soff + (size_t)(2*t2+1)*512]);
            p[t2] = lo | (hi << 16);
        }
        *(uint4*)(w2T + doff) = make_uint4(p[0], p[1], p[2], p[3]);
    }
}

// ---------------- bf16 MFMA GEMM, pipelined K-loop (2-deep prefetch, counted vmcnt) ----------------
// ACT: 0 = none -> fp32 Cf (+ z*1048576 per k-slice, bias only on slice 0)
//      3 = gelu -> bf16 Cb ; 4 = fused QKV epilogue -> bf16 Cb
template<int BM, int BN, int WR, int WC, int ACT, int KS>
__global__ __launch_bounds__(WR*WC*64) void k_mgemm(
        const unsigned short* __restrict__ A, const unsigned short* __restrict__ Wt,
        const float* __restrict__ bias, const int* __restrict__ maskv,
        float* __restrict__ Cf, unsigned short* __restrict__ Cb,
        int N, int K, int lda, int ldc) {
    constexpr int THREADS = WR*WC*64;
    constexpr int WM = BM/WR, WN = BN/WC;
    constexpr int FM = WM/16, FN = WN/16;
    constexpr int AL = BM*4/THREADS;      // A gl_lds per thread per K-step
    constexpr int BL = BN*4/THREADS;      // B gl_lds per thread per K-step
    constexpr int NL = AL + BL;
    __shared__ __align__(16) unsigned short As[3][BM*32];
    __shared__ __align__(16) unsigned short Bs[3][BN*32];
    int tid = threadIdx.x;
    int lane = tid & 63;
    int l15 = lane & 15, lg = lane >> 4;
    int wid = tid >> 6;
    int wm = (wid / WC) * WM, wn = (wid % WC) * WN;
    int bm = blockIdx.y * BM, bn = blockIdx.x * BN;
    int kz = blockIdx.z;
    int ksl = K / KS;
    int kbeg = kz * ksl;
    int nt = ksl / 32;

    f32x4 acc[FM][FN] = {};

    int a_off = (wm + l15)*32 + lg*8;
    int b_off = lg*BN*8 + (wn + l15)*8;

    auto stage = [&](int buf, int ks) {
        int k0 = kbeg + ks*32;
#pragma unroll
        for (int i = 0; i < AL; ++i) {
            int s = tid + i*THREADS;
            int m = s >> 2, kq = s & 3;
            gl_lds16(A + (size_t)(bm + m)*lda + k0 + kq*8, &As[buf][s*8]);
        }
#pragma unroll
        for (int i = 0; i < BL; ++i) {
            int s = tid + i*THREADS;
            int kb = s / BN, n = s - kb*BN;
            gl_lds16(Wt + ((size_t)(k0/8 + kb)*N + bn + n)*8, &Bs[buf][s*8]);
        }
    };
    auto compute = [&](int buf) {
        bf16x8 af[FM], bfr[FN];
#pragma unroll
        for (int mi = 0; mi < FM; ++mi) af[mi] = *(const bf16x8*)&As[buf][a_off + mi*512];
#pragma unroll
        for (int ni = 0; ni < FN; ++ni) bfr[ni] = *(const bf16x8*)&Bs[buf][b_off + ni*128];
#pragma unroll
        for (int mi = 0; mi < FM; ++mi)
#pragma unroll
            for (int ni = 0; ni < FN; ++ni)
                acc[mi][ni] = __builtin_amdgcn_mfma_f32_16x16x32_bf16(af[mi], bfr[ni], acc[mi][ni], 0, 0, 0);
    };

    stage(0, 0);
    stage(1, 1);
    for (int t = 0; t < nt - 2; ++t) {
        stage((t + 2) % 3, t + 2);
        wait_vm<2*NL>();                       // step-t loads retired; t+1,t+2 stay in flight
        __builtin_amdgcn_s_barrier();
        __builtin_amdgcn_sched_barrier(0);
        compute(t % 3);
        __builtin_amdgcn_sched_barrier(0);
        __builtin_amdgcn_s_barrier();
    }
    wait_vm<NL>();
    __builtin_amdgcn_s_barrier();
    __builtin_amdgcn_sched_barrier(0);
    compute((nt - 2) % 3);
    __builtin_amdgcn_sched_barrier(0);
    __builtin_amdgcn_s_barrier();
    wait_vm<0>();
    __builtin_amdgcn_s_barrier();
    __builtin_amdgcn_sched_barrier(0);
    compute((nt - 1) % 3);

    int r0 = bm + wm + lg*4;
    int c0 = bn + wn + l15;
    float* Cfz = Cf + (size_t)kz * 1048576;
#pragma unroll
    for (int mi = 0; mi < FM; ++mi) {
#pragma unroll
        for (int ni = 0; ni < FN; ++ni) {
            int col = c0 + ni*16;
#pragma unroll
            for (int j = 0; j < 4; ++j) {
                int row = r0 + mi*16 + j;
                float c = acc[mi][ni][j];
                if (KS == 1 || kz == 0) c += bias[col];
                if (ACT == 4) {
                    int reg = col >> 9;
                    if (reg == 0) { c = (c > 0.f) ? c + 1.f : expf(c); }
                    else if (reg == 1) { c = (c > 0.f) ? c + 1.f : expf(c); c *= (maskv[row] != 0) ? 1.f : 0.f; }
                    Cb[(size_t)row*ldc + col] = f2bf(c);
                } else if (ACT == 3) {
                    c = 0.5f * c * (1.f + erff(c * 0.70710678118654752f));
                    Cb[(size_t)row*ldc + col] = f2bf(c);
                } else {
                    Cfz[(size_t)row*ldc + col] = c;
                }
            }
        }
    }
}

// ---------------- per-chunk partial K^T V (64x64) and sum(k) (64), bf16 in ----------------
__global__ __launch_bounds__(256) void k_cpart(
        const unsigned short* __restrict__ QKVb, float* __restrict__ Mpart, float* __restrict__ Upart) {
    int b = blockIdx.x;
    int c = b % NCH, h = (b / NCH) % NHEAD, n = b / (NCH * NHEAD);
    const unsigned short* Kp = QKVb + (size_t)(n*SEQL + c*CHUNK)*QSTR + 512 + h*64;
    const unsigned short* Vp = Kp + 512;
    __shared__ float Ks[8][64], Vs[8][64];
    int tid = threadIdx.x;
    int dk = tid >> 2, dv0 = (tid & 3) * 16;
    int lr = tid >> 5, lc = (tid & 31) * 2;
    float acc[16] = {};
    float uacc = 0.f;
    for (int s0 = 0; s0 < CHUNK; s0 += 8) {
        ushort2 k2 = *(const ushort2*)(Kp + (size_t)(s0 + lr)*QSTR + lc);
        ushort2 v2 = *(const ushort2*)(Vp + (size_t)(s0 + lr)*QSTR + lc);
        Ks[lr][lc] = bf2f(k2.x); Ks[lr][lc+1] = bf2f(k2.y);
        Vs[lr][lc] = bf2f(v2.x); Vs[lr][lc+1] = bf2f(v2.y);
        __syncthreads();
#pragma unroll
        for (int ss = 0; ss < 8; ++ss) {
            float kk = Ks[ss][dk];
#pragma unroll
            for (int j = 0; j < 16; ++j) acc[j] += kk * Vs[ss][dv0 + j];
        }
        if (tid < 64) {
#pragma unroll
            for (int ss = 0; ss < 8; ++ss) uacc += Ks[ss][tid];
        }
        __syncthreads();
    }
    size_t base = ((size_t)(n*NHEAD + h)*NCH + c) * 4096;
#pragma unroll
    for (int j = 0; j < 16; ++j) Mpart[base + (size_t)dk*64 + dv0 + j] = acc[j];
    if (tid < 64) Upart[((size_t)(n*NHEAD + h)*NCH + c)*64 + tid] = uacc;
}

// ---------------- MFMA chunk attention (prefix folded in from Mpart/Upart) ----------------
__global__ __launch_bounds__(512) void k_cattend(
        const unsigned short* __restrict__ QKVb, const float* __restrict__ Mpart,
        const float* __restrict__ Upart, unsigned short* __restrict__ Ab) {
    int b = blockIdx.x;
    int c = b % NCH, h = (b / NCH) % NHEAD, n = b / (NCH * NHEAD);
    int nh = n*NHEAD + h;
    int tid = threadIdx.x;
    int wid = tid >> 6, lane = tid & 63;
    int l15 = lane & 15, lg = lane >> 4;
    __shared__ __align__(16) unsigned short Vt[64*200];   // [vd][j] j=0..191 (V | P)
    __shared__ __align__(16) unsigned short St[11264];
    __shared__ float wf[64];
    int rowbase = n*SEQL + c*CHUNK;

    {
        int j = tid & 127, vd0 = (tid >> 7) * 16;
        const unsigned short* vp = QKVb + (size_t)(rowbase + j)*QSTR + 1024 + h*64 + vd0;
        uint4 u0 = *(const uint4*)vp;
        uint4 u1 = *(const uint4*)(vp + 8);
        const unsigned short* e0 = (const unsigned short*)&u0;
        const unsigned short* e1 = (const unsigned short*)&u1;
#pragma unroll
        for (int t = 0; t < 8; ++t) Vt[(vd0 + t)*200 + j] = e0[t];
#pragma unroll
        for (int t = 0; t < 8; ++t) Vt[(vd0 + 8 + t)*200 + j] = e1[t];
    }
    {
        int d = tid & 63, vd0 = (tid >> 6) * 8;
        float pr[8] = {};
        for (int cc = 0; cc < c; ++cc) {
            const float* pp = Mpart + ((size_t)nh*NCH + cc)*4096 + (size_t)d*64 + vd0;
            float4 p0 = *(const float4*)pp;
            float4 p1 = *(const float4*)(pp + 4);
            pr[0]+=p0.x; pr[1]+=p0.y; pr[2]+=p0.z; pr[3]+=p0.w;
            pr[4]+=p1.x; pr[5]+=p1.y; pr[6]+=p1.z; pr[7]+=p1.w;
        }
#pragma unroll
        for (int t = 0; t < 8; ++t) Vt[(vd0 + t)*200 + 128 + d] = f2bf(pr[t]);
    }
    if (tid < 64) {
        float u = 0.f;
        for (int cc = 0; cc < c; ++cc) u += Upart[((size_t)nh*NCH + cc)*64 + tid];
        wf[tid] = u;
    }

    int r0 = wid * 16;
    int koff = lg * 8;
    const unsigned short* qp = QKVb + (size_t)(rowbase + r0 + l15)*QSTR + h*64 + koff;
    uint4 uq0 = *(const uint4*)qp;
    uint4 uq1 = *(const uint4*)(qp + 32);
    bf16x8 aq0 = *(bf16x8*)&uq0;
    bf16x8 aq1 = *(bf16x8*)&uq1;

    int nact = (wid & ~1) + 2;
    int sstr_ = 32*((wid >> 1) + 1) + 8;
    int p_ = wid >> 1;
    int sig = p_*(p_+1) + (wid & 1)*(p_+1);
    int stoff_ = 128*wid + 512*sig;

    float rsum[4] = {0.f, 0.f, 0.f, 0.f};
    for (int nt = 0; nt < nact; ++nt) {
        int j0 = nt*16;
        const unsigned short* kp = QKVb + (size_t)(rowbase + j0 + l15)*QSTR + 512 + h*64 + koff;
        uint4 uk0 = *(const uint4*)kp;
        uint4 uk1 = *(const uint4*)(kp + 32);
        f32x4 s = {0.f, 0.f, 0.f, 0.f};
        s = __builtin_amdgcn_mfma_f32_16x16x32_bf16(aq0, *(bf16x8*)&uk0, s, 0, 0, 0);
        s = __builtin_amdgcn_mfma_f32_16x16x32_bf16(aq1, *(bf16x8*)&uk1, s, 0, 0, 0);
        int jcol = j0 + l15;
#pragma unroll
        for (int r = 0; r < 4; ++r) {
            int irow = r0 + lg*4 + r;
            float sv = (jcol <= irow) ? s[r] : 0.f;
            rsum[r] += sv;
            St[stoff_ + (lg*4 + r)*sstr_ + jcol] = f2bf(sv);
        }
    }
    __syncthreads();

    float qw = 0.f;
    const unsigned short* q0e = (const unsigned short*)&uq0;
    const unsigned short* q1e = (const unsigned short*)&uq1;
#pragma unroll
    for (int jj = 0; jj < 8; ++jj) {
        qw += bf2f(q0e[jj]) * wf[koff + jj];
        qw += bf2f(q1e[jj]) * wf[32 + koff + jj];
    }
    qw += __shfl_xor(qw, 16);
    qw += __shfl_xor(qw, 32);

    f32x4 o[4] = {};
    int nkr = (wid >> 1) + 1;
    for (int ks = 0; ks < nkr; ++ks) {
        bf16x8 as = *(bf16x8*)&St[stoff_ + l15*sstr_ + ks*32 + koff];
#pragma unroll
        for (int nt = 0; nt < 4; ++nt) {
            bf16x8 bv = *(bf16x8*)&Vt[(nt*16 + l15)*200 + ks*32 + koff];
            o[nt] = __builtin_amdgcn_mfma_f32_16x16x32_bf16(as, bv, o[nt], 0, 0, 0);
        }
    }
#pragma unroll
    for (int kk = 0; kk < 2; ++kk) {
        bf16x8 as = kk ? aq1 : aq0;
#pragma unroll
        for (int nt = 0; nt < 4; ++nt) {
            bf16x8 bv = *(bf16x8*)&Vt[(nt*16 + l15)*200 + 128 + kk*32 + koff];
            o[nt] = __builtin_amdgcn_mfma_f32_16x16x32_bf16(as, bv, o[nt], 0, 0, 0);
        }
    }

#pragma unroll
    for (int r = 0; r < 4; ++r) {
        float v = rsum[r];
        v += __shfl_xor(v, 1); v += __shfl_xor(v, 2);
        v += __shfl_xor(v, 4); v += __shfl_xor(v, 8);
        rsum[r] = v;
    }
#pragma unroll
    for (int r = 0; r < 4; ++r) {
        float qwr = __shfl(qw, lg*4 + r);
        float z = 1.f / (rsum[r] + qwr + ATT_EPS_F);
        int orow = rowbase + r0 + lg*4 + r;
        unsigned short* op = Ab + (size_t)orow*EMB + h*64 + l15;
#pragma unroll
        for (int nt = 0; nt < 4; ++nt)
            op[nt*16] = f2bf(o[nt][r] * z);
    }
}

// ---------------- residual (nsl slices) + LayerNorm -> fp32 Y and bf16 Yb ----------------
__global__ __launch_bounds__(256) void k_ln(
        const float* __restrict__ X, const float* __restrict__ R, int nsl,
        const float* __restrict__ g, const float* __restrict__ bb,
        float* __restrict__ Y, unsigned short* __restrict__ Yb) {
    int row = blockIdx.x, tid = threadIdx.x;
    float2 v = *(const float2*)(X + (size_t)row*EMB + tid*2);
    for (int z = 0; z < nsl; ++z) {
        float2 r = *(const float2*)(R + (size_t)z*1048576 + (size_t)row*EMB + tid*2);
        v.x += r.x; v.y += r.y;
    }
    float s = v.x + v.y, ss = v.x*v.x + v.y*v.y;
#pragma unroll
    for (int off = 32; off; off >>= 1) {
        s  += __shfl_down(s, off);
        ss += __shfl_down(ss, off);
    }
    __shared__ float sb[4], ssb[4];
    int wid = tid >> 6, lane = tid & 63;
    if (!lane) { sb[wid] = s; ssb[wid] = ss; }
    __syncthreads();
    float tot  = sb[0] + sb[1] + sb[2] + sb[3];
    float tots = ssb[0] + ssb[1] + ssb[2] + ssb[3];
    float mean = tot * (1.f/EMB);
    float var  = tots * (1.f/EMB) - mean*mean;
    float inv  = rsqrtf(var + LN_EPS_F);
    int e = tid*2;
    float2 o;
    o.x = (v.x - mean)*inv*g[e]   + bb[e];
    o.y = (v.y - mean)*inv*g[e+1] + bb[e+1];
    *(float2*)(Y + (size_t)row*EMB + e) = o;
    ushort2 ob; ob.x = f2bf(o.x); ob.y = f2bf(o.y);
    *(ushort2*)(Yb + (size_t)row*EMB + e) = ob;
}

// ---------------- fused final LN + head (512->17), 8 rows/block ----------------
__global__ __launch_bounds__(256) void k_lnhead(
        const float* __restrict__ X, const float* __restrict__ g, const float* __restrict__ bb,
        const float* __restrict__ Wh, float* __restrict__ out) {
    __shared__ float ys[8][512];
    __shared__ float whs[512*17];
    int tid = threadIdx.x;
    for (int i = tid; i < 512*17; i += 256) whs[i] = Wh[i];

    int row = tid >> 5, l32 = tid & 31;
    int rg = blockIdx.x * 8 + row;
    const float* xr = X + (size_t)rg*EMB + l32*16;
    float v[16];
    float s = 0.f, ss = 0.f;
#pragma unroll
    for (int i = 0; i < 4; ++i) {
        float4 a = *(const float4*)(xr + i*4);
        v[i*4+0]=a.x; v[i*4+1]=a.y; v[i*4+2]=a.z; v[i*4+3]=a.w;
        s += a.x+a.y+a.z+a.w;
        ss += a.x*a.x+a.y*a.y+a.z*a.z+a.w*a.w;
    }
#pragma unroll
    for (int off = 1; off < 32; off <<= 1) { s += __shfl_xor(s, off); ss += __shfl_xor(ss, off); }
    float mean = s * (1.f/EMB);
    float var  = ss * (1.f/EMB) - mean*mean;
    float inv  = rsqrtf(var + LN_EPS_F);
    int c0 = l32*16;
#pragma unroll
    for (int i = 0; i < 16; ++i) {
        float y = (v[i] - mean)*inv*g[c0+i] + bb[c0+i];
        ys[row][c0+i] = y;
    }
    __syncthreads();

    float part[17];
#pragma unroll
    for (int cc = 0; cc < 17; ++cc) part[cc] = 0.f;
    for (int kk = 0; kk < 16; ++kk) {
        int k = c0 + kk;
        float yv = ys[row][k];
#pragma unroll
        for (int cc = 0; cc < 17; ++cc) part[cc] += yv * whs[k*17 + cc];
    }
#pragma unroll
    for (int cc = 0; cc < 17; ++cc) {
        float pv = part[cc];
#pragma unroll
        for (int off = 1; off < 32; off <<= 1) pv += __shfl_xor(pv, off);
        if (l32 == 0) out[(size_t)rg*17 + cc] = pv;
    }
}

extern "C" void kernel_launch(void* const* d_in, const int* in_sizes, int n_in,
                              void* d_out, int out_size, void* d_ws, size_t ws_size,
                              hipStream_t stream) {
    (void)in_sizes; (void)n_in; (void)out_size; (void)ws_size;
    const int*   value = (const int*)d_in[0];
    const int*   depth = (const int*)d_in[1];
    const int*   pos   = (const int*)d_in[2];
    const float* sos   = (const float*)d_in[3];
    const float* tok   = (const float*)d_in[4];
    const float* dep   = (const float*)d_in[5];
    const float* spa   = (const float*)d_in[6];
    const float* Wq0   = (const float*)d_in[7];
    const float* Wk0   = (const float*)d_in[8];
    const float* Wv0   = (const float*)d_in[9];
    const float* Wo0   = (const float*)d_in[10];
    const float* bq0   = (const float*)d_in[11];
    const float* bk0   = (const float*)d_in[12];
    const float* bv0   = (const float*)d_in[13];
    const float* bo0   = (const float*)d_in[14];
    const float* ln1g  = (const float*)d_in[15];
    const float* ln1b  = (const float*)d_in[16];
    const float* ln2g  = (const float*)d_in[17];
    const float* ln2b  = (const float*)d_in[18];
    const float* W10   = (const float*)d_in[19];
    const float* b10   = (const float*)d_in[20];
    const float* W20   = (const float*)d_in[21];
    const float* b20   = (const float*)d_in[22];
    const float* lnfg  = (const float*)d_in[23];
    const float* lnfb  = (const float*)d_in[24];
    const float* Wh    = (const float*)d_in[25];
    float* out = (float*)d_out;
    float* ws  = (float*)d_ws;

    float*          X     = ws;                                  // 1048576 f
    unsigned short* Xb    = (unsigned short*)(ws + 1048576);     // 524288 f
    unsigned short* QKVb  = (unsigned short*)(ws + 1572864);     // 1572864 f
    unsigned short* Ab    = (unsigned short*)(ws + 3145728);     // 524288 f
    unsigned short* Hb    = (unsigned short*)(ws + 1572864);     // alias QKVb+Ab (2048x2048 bf16)
    float*          Mpart = ws + 3670016;                        // 524288 f
    float*          Upart = ws + 4194304;                        // 8192 f
    float*          AO    = ws + 4202496;                        // 4 x 1048576 f (split-K slices)
    float*          bqkv  = ws + 8396800;                        // 6144 f
    unsigned short* wAll  = (unsigned short*)(ws + 8402944);     // 4 x 3145728 sh

    k_embed<<<NROWS, 128, 0, stream>>>(value, depth, pos, sos, tok, dep, spa, X, Xb);
    k_wconv<<<6168, 256, 0, stream>>>(Wq0, Wk0, Wv0, Wo0, W10, W20, bq0, bk0, bv0, wAll, bqkv);

    for (int L = 0; L < NLAYER; ++L) {
        unsigned short* lay  = wAll + (size_t)L*3145728;
        unsigned short* qkvT = lay;
        unsigned short* woT  = lay + 786432;
        unsigned short* w1T  = lay + 1048576;
        unsigned short* w2T  = lay + 2097152;

        // QKV: 64x128 tiles -> 12x32 = 384 blocks
        k_mgemm<64,128,2,2,4,1><<<dim3(12,32), 256, 0, stream>>>(
            Xb, qkvT, bqkv + L*1536, value, nullptr, QKVb, 1536, 512, 512, 1536);

        k_cpart<<<NBATCH*NHEAD*NCH, 256, 0, stream>>>(QKVb, Mpart, Upart);
        k_cattend<<<NBATCH*NHEAD*NCH, 512, 0, stream>>>(QKVb, Mpart, Upart, Ab);

        // Wo: 64x64, split-K=2 -> 8x32x2 = 512 blocks
        k_mgemm<64,64,2,2,0,2><<<dim3(8,32,2), 256, 0, stream>>>(
            Ab, woT, bo0 + (size_t)L*EMB, nullptr, AO, nullptr, 512, 512, 512, 512);
        k_ln<<<NROWS, 256, 0, stream>>>(X, AO, 2, ln1g + (size_t)L*EMB, ln1b + (size_t)L*EMB, X, Xb);

        // FF1: 64x128 tiles -> 16x32 = 512 blocks
        k_mgemm<64,128,2,2,3,1><<<dim3(16,32), 256, 0, stream>>>(
            Xb, w1T, b10 + (size_t)L*FFDIM, nullptr, nullptr, Hb, 2048, 512, 512, 2048);

        // FF2: 64x64, split-K=4 -> 8x32x4 = 1024 blocks (K-slice 512)
        k_mgemm<64,64,2,2,0,4><<<dim3(8,32,4), 256, 0, stream>>>(
            Hb, w2T, b20 + (size_t)L*EMB, nullptr, AO, nullptr, 512, 2048, 2048, 512);
        k_ln<<<NROWS, 256, 0, stream>>>(X, AO, 4, ln2g + (size_t)L*EMB, ln2b + (size_t)L*EMB, X, Xb);
    }
    k_lnhead<<<NROWS/8, 256, 0, stream>>>(X, lnfg, lnfb, Wh, out);
}